// Round 4
// baseline (644.520 us; speedup 1.0000x reference)
//
#include <hip/hip_runtime.h>

// MemoryCompressedAttention: B=4, S=4096, D=1024, H=16, DK=64, CR=3, pad=2, Lc=1366.
// bf16 MFMA pipeline: cast -> conv-as-gemm(kpad) -> projections -> MFMA flash attn -> out proj.
// R3: swapped-QK in-register softmax attn; z-batched GEMM pairs.
// R4: gemm_mfma_k 2-phase double-buffered prefetch-under-compute (64KB LDS, lb(256,2));
//     attn lsum via ones-MFMA (kills 32 v_add/tile + epilogue shuffles);
//     weight casts merged into one z-batched launch.

#define DM   1024
#define NH   16
#define DKH  64
#define BB   4
#define SQ   4096
#define LCC  1366
#define LCP  1408   // padded Lc for transposed V rows (22*64)
#define SPAD 4098   // padded seq = im2col rows * 3

#define QSC  0.18033688011f   // 0.125 * log2(e): fold softmax scale + base-2 exp into Wq

typedef unsigned short u16;
using short8 = __attribute__((ext_vector_type(8))) short;
using f32x4  = __attribute__((ext_vector_type(4))) float;
using us4    = __attribute__((ext_vector_type(4))) unsigned short;
using us8    = __attribute__((ext_vector_type(8))) unsigned short;

__device__ __forceinline__ u16 f2bf(float f) {
    unsigned u = __float_as_uint(f);
    u += 0x7fffu + ((u >> 16) & 1u);      // RTNE
    return (u16)(u >> 16);
}

// async global->LDS 16B: LDS dest is wave-uniform base + lane*16 (pass per-lane ptr matching that).
__device__ __forceinline__ void gl_lds16(const void* g, void* l) {
    __builtin_amdgcn_global_load_lds(
        (__attribute__((address_space(1))) unsigned int*)(uintptr_t)g,
        (__attribute__((address_space(3))) unsigned int*)l,
        16, 0, 0);
}

// ---------------- casts ----------------
__global__ __launch_bounds__(256) void cast4_k(const float* __restrict__ in, u16* __restrict__ out,
                                               int n4, float scale) {
    int i = blockIdx.x * 256 + threadIdx.x;
    if (i >= n4) return;
    float4 v = ((const float4*)in)[i];
    us4 o;
    o[0] = f2bf(v.x * scale); o[1] = f2bf(v.y * scale);
    o[2] = f2bf(v.z * scale); o[3] = f2bf(v.w * scale);
    ((us4*)out)[i] = o;
}

// all four weight matrices in one launch (z selects); z==0 carries the folded q scale
__global__ __launch_bounds__(256) void cast4w_k(
    const float* __restrict__ w0, const float* __restrict__ w1,
    const float* __restrict__ w2, const float* __restrict__ w3,
    u16* __restrict__ o0, u16* __restrict__ o1, u16* __restrict__ o2, u16* __restrict__ o3,
    float qsc) {
    int z = blockIdx.z;
    const float* in = (z == 0) ? w0 : (z == 1) ? w1 : (z == 2) ? w2 : w3;
    u16* out        = (z == 0) ? o0 : (z == 1) ? o1 : (z == 2) ? o2 : o3;
    float scale     = (z == 0) ? qsc : 1.0f;
    int i = blockIdx.x * 256 + threadIdx.x;
    float4 v = ((const float4*)in)[i];
    us4 o;
    o[0] = f2bf(v.x * scale); o[1] = f2bf(v.y * scale);
    o[2] = f2bf(v.z * scale); o[3] = f2bf(v.w * scale);
    ((us4*)out)[i] = o;
}

// kpad[b, s, :] = (s<2) ? 0 : key[b, s-2, :]   (bf16); z batches the key/value pair
__global__ __launch_bounds__(256) void cast_pad2_k(const float* __restrict__ in0, u16* __restrict__ out0,
                                                   const float* __restrict__ in1, u16* __restrict__ out1) {
    const float* in = blockIdx.z ? in1 : in0;
    u16* out        = blockIdx.z ? out1 : out0;
    int i = blockIdx.x * 256 + threadIdx.x;
    const int n4 = BB * SPAD * DM / 4;
    if (i >= n4) return;
    int e   = i * 4;
    int b   = e / (SPAD * DM);
    int rem = e - b * (SPAD * DM);
    int s   = rem >> 10;
    int d   = rem & (DM - 1);
    us4 o = {0, 0, 0, 0};
    if (s >= 2) {
        float4 v = *(const float4*)(in + (size_t)(b * SQ + (s - 2)) * DM + d);
        o[0] = f2bf(v.x); o[1] = f2bf(v.y); o[2] = f2bf(v.z); o[3] = f2bf(v.w);
    }
    ((us4*)out)[i] = o;
}

// wc2[o][r*1024+i] = conv_w[o][i][r]  (bf16)
__global__ __launch_bounds__(256) void permcast_conv_k(const float* __restrict__ cw, u16* __restrict__ wc2) {
    int i = blockIdx.x * 256 + threadIdx.x;
    const int n4 = DM * DM * 3 / 4;
    if (i >= n4) return;
    int e   = i * 4;
    int o   = e / 3072;
    int rem = e - o * 3072;
    int r   = rem >> 10;
    int ii  = rem & 1023;
    us4 q;
    #pragma unroll
    for (int t = 0; t < 4; ++t) q[t] = f2bf(cw[(size_t)(o * DM + ii + t) * 3 + r]);
    ((us4*)wc2)[i] = q;
}

// vt[(b*16+h)*64 + d][cp] = vp[b*1366 + j0 + pi(cp)][h*64+d], zero for j>=1366; row stride LCP.
// pi(cp): cp = ks*32 + quad*8 + j  ->  k = (ks + 2*(j>>2))*16 + quad*4 + (j&3).
// Matches attn's in-register P layout (PV A-frag slot (ks,quad,j) = lane's own sc value).
__global__ __launch_bounds__(256) void transpose_v_k(const u16* __restrict__ vp, u16* __restrict__ vt) {
    __shared__ u16 t[64 * 65];   // stride 65: break power-of-2 bank aliasing
    const int tid = threadIdx.x;
    const int j0 = blockIdx.x * 64;
    const int bh = blockIdx.y, b = bh >> 4, h = bh & 15;
    #pragma unroll
    for (int it = 0; it < 2; ++it) {
        int cc = tid + it * 256;
        int j = cc >> 3, d0 = (cc & 7) * 8;
        int jj = j0 + j;
        us8 v = {0, 0, 0, 0, 0, 0, 0, 0};
        if (jj < LCC) v = *(const us8*)(vp + (size_t)(b * LCC + jj) * DM + h * DKH + d0);
        #pragma unroll
        for (int q = 0; q < 8; ++q) t[(d0 + q) * 65 + j] = v[q];
    }
    __syncthreads();
    #pragma unroll
    for (int it = 0; it < 2; ++it) {
        int cc = tid + it * 256;
        int d = cc >> 3, q0 = (cc & 7) * 8;
        us8 v;
        #pragma unroll
        for (int q = 0; q < 8; ++q) {
            int cp = q0 + q;                              // stored (permuted) col
            int ks = cp >> 5, qd = (cp >> 3) & 3, j = cp & 7;
            int k  = (ks + 2 * (j >> 2)) * 16 + qd * 4 + (j & 3);   // original col
            v[q] = t[d * 65 + k];
        }
        *(us8*)(vt + (size_t)(bh * DKH + d) * LCP + j0 + q0) = v;
    }
}

// ---------------- MFMA GEMM: C[n,o] = sum_k A[n,k]*Bw[o,k] + bias[o]*bscale ----------------
// blockIdx.z selects problem 0/1 (batched pairs share N, K, cf32, bscale).
// 2-phase double-buffered: stage(t+1) issued right after the barrier that publishes tile t,
// so global-load latency hides under tile t's MFMA (same structure as attn_mfma_k).
__global__ __launch_bounds__(256, 2) void gemm_mfma_k(
    const u16* __restrict__ A0, const u16* __restrict__ B0, const float* __restrict__ bias0, void* __restrict__ C0,
    const u16* __restrict__ A1, const u16* __restrict__ B1, const float* __restrict__ bias1, void* __restrict__ C1,
    int N, int K, int cf32, float bscale)
{
    const u16* A      = blockIdx.z ? A1 : A0;
    const u16* Bw     = blockIdx.z ? B1 : B0;
    const float* bias = blockIdx.z ? bias1 : bias0;
    void* C           = blockIdx.z ? C1 : C0;

    __shared__ u16 lds[2 * 16384];   // 64 KB: [buf][As 128x64 | Bs 128x64], XOR-swizzled rows
    const int tid = threadIdx.x, wave = tid >> 6, lane = tid & 63;
    const int quad = lane >> 4, l15 = lane & 15;
    const int n0 = blockIdx.y * 128, o0 = blockIdx.x * 128;
    const int wm = (wave >> 1) * 64, wn = (wave & 1) * 64;
    const int srow = (lane >> 3), sc8 = (lane & 7);

    f32x4 acc[4][4];
    #pragma unroll
    for (int a = 0; a < 4; ++a)
        #pragma unroll
        for (int b = 0; b < 4; ++b)
            #pragma unroll
            for (int r = 0; r < 4; ++r) acc[a][b][r] = 0.0f;

    auto stage = [&](int kt, u16* base) {
        #pragma unroll
        for (int i = 0; i < 4; ++i) {
            int is  = wave * 4 + i;
            int row = is * 8 + srow;
            int c   = sc8 ^ (row & 7);
            int ra  = n0 + row; if (ra > N - 1) ra = N - 1;
            gl_lds16(A  + (size_t)ra * K + kt + c * 8,          base + is * 512 + lane * 8);
            gl_lds16(Bw + (size_t)(o0 + row) * K + kt + c * 8,  base + 8192 + is * 512 + lane * 8);
        }
    };

    stage(0, lds);
    int cur = 0;
    const int nk = K >> 6;
    for (int ki = 0; ki < nk; ++ki) {
        __syncthreads();                        // publish buf[cur] (drains its gl_lds)
        if (ki + 1 < nk) stage((ki + 1) << 6, lds + (cur ^ 1) * 16384);
        const u16* As = lds + cur * 16384;
        const u16* Bs = As + 8192;
        #pragma unroll
        for (int ks = 0; ks < 2; ++ks) {
            short8 af[4], bf[4];
            #pragma unroll
            for (int mi = 0; mi < 4; ++mi) {
                int m = wm + mi * 16 + l15;
                int c = (ks * 4 + quad) ^ (m & 7);
                af[mi] = *(const short8*)(As + m * 64 + c * 8);
            }
            #pragma unroll
            for (int nj = 0; nj < 4; ++nj) {
                int n = wn + nj * 16 + l15;
                int c = (ks * 4 + quad) ^ (n & 7);
                bf[nj] = *(const short8*)(Bs + n * 64 + c * 8);
            }
            #pragma unroll
            for (int mi = 0; mi < 4; ++mi)
                #pragma unroll
                for (int nj = 0; nj < 4; ++nj)
                    acc[mi][nj] = __builtin_amdgcn_mfma_f32_16x16x32_bf16(af[mi], bf[nj], acc[mi][nj], 0, 0, 0);
        }
        cur ^= 1;
    }
    #pragma unroll
    for (int mi = 0; mi < 4; ++mi) {
        #pragma unroll
        for (int r = 0; r < 4; ++r) {
            int n = n0 + wm + mi * 16 + quad * 4 + r;
            if (n < N) {
                #pragma unroll
                for (int nj = 0; nj < 4; ++nj) {
                    int o = o0 + wn + nj * 16 + l15;
                    float v = acc[mi][nj][r] + bias[o] * bscale;
                    if (cf32) ((float*)C)[(size_t)n * DM + o] = v;
                    else      ((u16*)C)[(size_t)n * DM + o] = f2bf(v);
                }
            }
        }
    }
}

// ---------------- MFMA flash attention, swapped-QK in-register softmax ----------------
// QK^T computed as mfma(K, Q) -> S[k][q]; P stays in registers (32 exp2 + 16 cvt_pk/tile).
// V columns pre-permuted by pi (transpose_v_k) so P fragments feed PV directly.
// Row-sums via MFMA against a ones-B-fragment: lacc[qg][r] = sum_k P[k][q_row] — already
// indexed by output row, no cross-lane reduce needed.
__global__ __launch_bounds__(256, 3) void attn_mfma_k(
    const u16* __restrict__ qp, const u16* __restrict__ kp,
    const u16* __restrict__ vt, u16* __restrict__ xo)
{
    __shared__ u16 lds[4 * 4096];   // 32 KB: [buf0: K|V][buf1: K|V]; Q staged through buf0 region
    const int tid = threadIdx.x, wave = tid >> 6, lane = tid & 63;
    const int quad = lane >> 4, l15 = lane & 15;
    const int bh = blockIdx.y, b = bh >> 4, h = bh & 15;
    const int s0 = blockIdx.x * 128;
    const int wq = wave * 32;
    const int srow = lane >> 3, sc8 = lane & 7;

    // ---- stage Q (128x64) into lds[0:8192] (overlaps buf0), then hoist to registers ----
    #pragma unroll
    for (int i = 0; i < 4; ++i) {
        int is = wave * 4 + i;
        int row = is * 8 + srow;
        int c = sc8 ^ (row & 7);
        gl_lds16(qp + (size_t)(b * SQ + s0 + row) * DM + h * DKH + c * 8,
                 lds + is * 512 + lane * 8);
    }
    __syncthreads();
    short8 qfr[2][2];   // [qg][ks]: B-frag = 8 contiguous d at row q = wq + qg*16 + l15
    #pragma unroll
    for (int qg = 0; qg < 2; ++qg) {
        int m = wq + qg * 16 + l15;
        #pragma unroll
        for (int ks = 0; ks < 2; ++ks) {
            int c = (ks * 4 + quad) ^ (m & 7);
            qfr[qg][ks] = *(const short8*)(lds + m * 64 + c * 8);
        }
    }
    __syncthreads();   // all waves done reading Q before buf0 overwrite

    f32x4 oacc[2][4], lacc[2];
    #pragma unroll
    for (int a = 0; a < 2; ++a) {
        #pragma unroll
        for (int r = 0; r < 4; ++r) lacc[a][r] = 0.0f;
        #pragma unroll
        for (int d = 0; d < 4; ++d)
            #pragma unroll
            for (int r = 0; r < 4; ++r) oacc[a][d][r] = 0.0f;
    }
    union { unsigned u[4]; short8 s; } onesu;
    #pragma unroll
    for (int i = 0; i < 4; ++i) onesu.u[i] = 0x3f803f80u;   // bf16 1.0 x8
    const short8 ones = onesu.s;

    // stage tile 0 into buf0
    #pragma unroll
    for (int i = 0; i < 2; ++i) {
        int is = wave * 2 + i;
        int row = is * 8 + srow;
        int c = sc8 ^ (row & 7);
        int j = row; if (j > LCC - 1) j = LCC - 1;
        gl_lds16(kp + (size_t)(b * LCC + j) * DM + h * DKH + c * 8, lds + is * 512 + lane * 8);
        gl_lds16(vt + (size_t)(bh * DKH + row) * LCP + c * 8,       lds + 4096 + is * 512 + lane * 8);
    }

    int cur = 0;
    for (int t = 0; t < 22; ++t) {
        const int j0 = t * 64;
        __syncthreads();               // publish buf[cur] (drains its gl_lds)
        if (t < 21) {                  // prefetch next tile under this tile's compute
            int nj0 = j0 + 64;
            u16* base = lds + (cur ^ 1) * 8192;
            #pragma unroll
            for (int i = 0; i < 2; ++i) {
                int is = wave * 2 + i;
                int row = is * 8 + srow;
                int c = sc8 ^ (row & 7);
                int j = nj0 + row; if (j > LCC - 1) j = LCC - 1;
                gl_lds16(kp + (size_t)(b * LCC + j) * DM + h * DKH + c * 8, base + is * 512 + lane * 8);
                gl_lds16(vt + (size_t)(bh * DKH + row) * LCP + nj0 + c * 8, base + 4096 + is * 512 + lane * 8);
            }
        }
        const u16* Kb = lds + cur * 8192;
        const u16* Vb = Kb + 4096;

        // ---- QK^T (A = K-tile rows, B = Q): sc[qg][nj] = S[k][q] ----
        f32x4 sc[2][4];
        #pragma unroll
        for (int a = 0; a < 2; ++a)
            #pragma unroll
            for (int n = 0; n < 4; ++n)
                #pragma unroll
                for (int r = 0; r < 4; ++r) sc[a][n][r] = 0.0f;
        __builtin_amdgcn_s_setprio(1);
        #pragma unroll
        for (int ks = 0; ks < 2; ++ks) {
            short8 kfr[4];
            #pragma unroll
            for (int nj = 0; nj < 4; ++nj) {
                int n = nj * 16 + l15;
                int c = (ks * 4 + quad) ^ (n & 7);
                kfr[nj] = *(const short8*)(Kb + n * 64 + c * 8);
            }
            #pragma unroll
            for (int qg = 0; qg < 2; ++qg)
                #pragma unroll
                for (int nj = 0; nj < 4; ++nj)
                    sc[qg][nj] = __builtin_amdgcn_mfma_f32_16x16x32_bf16(kfr[nj], qfr[qg][ks], sc[qg][nj], 0, 0, 0);
        }
        __builtin_amdgcn_s_setprio(0);

        // ---- softmax in-register: P = exp2(S) (scale folded into Wq), mask tail k ----
        const bool tail = (j0 + 64 > LCC);
        #pragma unroll
        for (int qg = 0; qg < 2; ++qg) {
            #pragma unroll
            for (int nj = 0; nj < 4; ++nj) {
                #pragma unroll
                for (int r = 0; r < 4; ++r) {
                    float p = __builtin_amdgcn_exp2f(sc[qg][nj][r]);
                    if (tail && (j0 + nj * 16 + quad * 4 + r) >= LCC) p = 0.0f;
                    sc[qg][nj][r] = p;
                }
            }
        }
        // ---- pack P into PV A-frags (lane-local; slot j -> (nj = ks+2*(j>>2), r = j&3)) ----
        short8 pa[2][2];
        #pragma unroll
        for (int qg = 0; qg < 2; ++qg) {
            #pragma unroll
            for (int ks = 0; ks < 2; ++ks) {
                unsigned w0, w1, w2, w3;
                asm("v_cvt_pk_bf16_f32 %0, %1, %2" : "=v"(w0) : "v"(sc[qg][ks][0]),     "v"(sc[qg][ks][1]));
                asm("v_cvt_pk_bf16_f32 %0, %1, %2" : "=v"(w1) : "v"(sc[qg][ks][2]),     "v"(sc[qg][ks][3]));
                asm("v_cvt_pk_bf16_f32 %0, %1, %2" : "=v"(w2) : "v"(sc[qg][ks + 2][0]), "v"(sc[qg][ks + 2][1]));
                asm("v_cvt_pk_bf16_f32 %0, %1, %2" : "=v"(w3) : "v"(sc[qg][ks + 2][2]), "v"(sc[qg][ks + 2][3]));
                union { unsigned u[4]; short8 s; } cv;
                cv.u[0] = w0; cv.u[1] = w1; cv.u[2] = w2; cv.u[3] = w3;
                pa[qg][ks] = cv.s;
            }
        }
        // ---- PV + row-sum: oacc += P*V, lacc += P*ones ----
        __builtin_amdgcn_s_setprio(1);
        #pragma unroll
        for (int ks = 0; ks < 2; ++ks) {
            short8 vfr[4];
            #pragma unroll
            for (int dj = 0; dj < 4; ++dj) {
                int d = dj * 16 + l15;
                int c = (ks * 4 + quad) ^ (d & 7);
                vfr[dj] = *(const short8*)(Vb + d * 64 + c * 8);
            }
            #pragma unroll
            for (int qg = 0; qg < 2; ++qg) {
                #pragma unroll
                for (int dj = 0; dj < 4; ++dj)
                    oacc[qg][dj] = __builtin_amdgcn_mfma_f32_16x16x32_bf16(pa[qg][ks], vfr[dj], oacc[qg][dj], 0, 0, 0);
                lacc[qg] = __builtin_amdgcn_mfma_f32_16x16x32_bf16(pa[qg][ks], ones, lacc[qg], 0, 0, 0);
            }
        }
        __builtin_amdgcn_s_setprio(0);
        cur ^= 1;
    }

    // ---- epilogue: lacc[qg][r] already holds the row-sum for output row quad*4+r ----
    #pragma unroll
    for (int qg = 0; qg < 2; ++qg) {
        #pragma unroll
        for (int r = 0; r < 4; ++r) {
            float inv = 1.0f / lacc[qg][r];
            int s = s0 + wq + qg * 16 + quad * 4 + r;
            #pragma unroll
            for (int dj = 0; dj < 4; ++dj)
                xo[(size_t)(b * SQ + s) * DM + h * DKH + dj * 16 + l15] = f2bf(oacc[qg][dj][r] * inv);
        }
    }
}

extern "C" void kernel_launch(void* const* d_in, const int* in_sizes, int n_in,
                              void* d_out, int out_size, void* d_ws, size_t ws_size,
                              hipStream_t stream)
{
    const float* query  = (const float*)d_in[0];
    const float* key    = (const float*)d_in[1];
    const float* value  = (const float*)d_in[2];
    const float* Wq     = (const float*)d_in[3];
    const float* bq     = (const float*)d_in[4];
    const float* Wk     = (const float*)d_in[5];
    const float* bk     = (const float*)d_in[6];
    const float* Wv     = (const float*)d_in[7];
    const float* bv     = (const float*)d_in[8];
    const float* Wo     = (const float*)d_in[9];
    const float* bo     = (const float*)d_in[10];
    const float* conv_w = (const float*)d_in[11];
    const float* conv_b = (const float*)d_in[12];
    float* out = (float*)d_out;

    u16* p = (u16*)d_ws;
    auto alloc = [&](size_t n) { u16* r = p; p += (n + 127) & ~(size_t)127; return r; };
    u16* qbf  = alloc((size_t)BB * SQ * DM);
    u16* kpad = alloc((size_t)BB * SPAD * DM);
    u16* vpad = alloc((size_t)BB * SPAD * DM);
    u16* wqb  = alloc((size_t)DM * DM);
    u16* wkb  = alloc((size_t)DM * DM);
    u16* wvb  = alloc((size_t)DM * DM);
    u16* wob  = alloc((size_t)DM * DM);
    u16* wc2b = alloc((size_t)DM * DM * 3);
    u16* kc   = alloc((size_t)BB * LCC * DM);
    u16* vc   = alloc((size_t)BB * LCC * DM);
    u16* kpj  = alloc((size_t)BB * LCC * DM);
    u16* vpj  = alloc((size_t)BB * LCC * DM);
    u16* qprj = alloc((size_t)BB * SQ * DM);
    u16* vtb  = alloc((size_t)BB * NH * DKH * LCP);
    u16* xo   = alloc((size_t)BB * SQ * DM);

    const int NC = BB * LCC;    // 5464
    const int NS = BB * SQ;     // 16384

    cast4_k<<<dim3(NS * DM / 4 / 256), 256, 0, stream>>>(query, qbf, NS * DM / 4, 1.0f);
    cast_pad2_k<<<dim3((BB * SPAD * DM / 4 + 255) / 256, 1, 2), 256, 0, stream>>>(key, kpad, value, vpad);
    cast4w_k<<<dim3(DM * DM / 4 / 256, 1, 4), 256, 0, stream>>>(Wq, Wk, Wv, Wo, wqb, wkb, wvb, wob, QSC);
    permcast_conv_k<<<dim3(DM * DM * 3 / 4 / 256), 256, 0, stream>>>(conv_w, wc2b);

    // conv compression as plain GEMM (batched pair): kpad flat view (B*1366, 3072) IS the im2col
    gemm_mfma_k<<<dim3(8, 43, 2), 256, 0, stream>>>(kpad, wc2b, conv_b, kc,
                                                    vpad, wc2b, conv_b, vc, NC, 3072, 0, 1.0f);

    // q projection (1/8*log2e folded into weights+bias)
    gemm_mfma_k<<<dim3(8, 128, 1), 256, 0, stream>>>(qbf, wqb, bq, qprj,
                                                     qbf, wqb, bq, qprj, NS, DM, 0, QSC);
    // k/v projections (batched pair)
    gemm_mfma_k<<<dim3(8, 43, 2), 256, 0, stream>>>(kc, wkb, bk, kpj,
                                                    vc, wvb, bv, vpj, NC, DM, 0, 1.0f);

    transpose_v_k<<<dim3(22, BB * NH), 256, 0, stream>>>(vpj, vtb);

    attn_mfma_k<<<dim3(SQ / 128, BB * NH), 256, 0, stream>>>(qprj, kpj, vtb, xo);

    gemm_mfma_k<<<dim3(8, 128, 1), 256, 0, stream>>>(xo, wob, bo, out,
                                                     xo, wob, bo, out, NS, DM, 1, 1.0f);
}

// Round 5
// 560.149 us; speedup vs baseline: 1.1506x; 1.1506x over previous
//
#include <hip/hip_runtime.h>

// MemoryCompressedAttention: B=4, S=4096, D=1024, H=16, DK=64, CR=3, pad=2, Lc=1366.
// bf16 MFMA pipeline: cast -> conv-as-gemm(kpad) -> projections -> MFMA flash attn -> out proj.
// R3: swapped-QK in-register softmax attn; z-batched GEMM pairs.
// R4: attn lsum via ones-MFMA; merged weight casts. (GEMM dbuf regressed -> reverted in R5.)
// R5: GEMM back to single-buffer lb(256,3); bijective XCD-chunked wgid swizzle on all
//     GEMMs + attn (R4 counters: A-panels fetched 8x = 268MB on q-proj; co-locate the 8
//     column-blocks of each panel on one XCD so its L2 serves them once).

#define DM   1024
#define NH   16
#define DKH  64
#define BB   4
#define SQ   4096
#define LCC  1366
#define LCP  1408   // padded Lc for transposed V rows (22*64)
#define SPAD 4098   // padded seq = im2col rows * 3

#define QSC  0.18033688011f   // 0.125 * log2(e): fold softmax scale + base-2 exp into Wq

typedef unsigned short u16;
using short8 = __attribute__((ext_vector_type(8))) short;
using f32x4  = __attribute__((ext_vector_type(4))) float;
using us4    = __attribute__((ext_vector_type(4))) unsigned short;
using us8    = __attribute__((ext_vector_type(8))) unsigned short;

__device__ __forceinline__ u16 f2bf(float f) {
    unsigned u = __float_as_uint(f);
    u += 0x7fffu + ((u >> 16) & 1u);      // RTNE
    return (u16)(u >> 16);
}

// async global->LDS 16B: LDS dest is wave-uniform base + lane*16 (pass per-lane ptr matching that).
__device__ __forceinline__ void gl_lds16(const void* g, void* l) {
    __builtin_amdgcn_global_load_lds(
        (__attribute__((address_space(1))) unsigned int*)(uintptr_t)g,
        (__attribute__((address_space(3))) unsigned int*)l,
        16, 0, 0);
}

// XCD-chunked bijective remap: wgid i -> j so that XCD k (= i%8 round-robin) executes a
// contiguous chunk of j-space, x fastest. Requires T%8==0 (all our grids satisfy this).
__device__ __forceinline__ int xcd_remap(int i, int T) {
    if (T & 7) return i;
    return (i & 7) * (T >> 3) + (i >> 3);
}

// ---------------- casts ----------------
__global__ __launch_bounds__(256) void cast4_k(const float* __restrict__ in, u16* __restrict__ out,
                                               int n4, float scale) {
    int i = blockIdx.x * 256 + threadIdx.x;
    if (i >= n4) return;
    float4 v = ((const float4*)in)[i];
    us4 o;
    o[0] = f2bf(v.x * scale); o[1] = f2bf(v.y * scale);
    o[2] = f2bf(v.z * scale); o[3] = f2bf(v.w * scale);
    ((us4*)out)[i] = o;
}

// all four weight matrices in one launch (z selects); z==0 carries the folded q scale
__global__ __launch_bounds__(256) void cast4w_k(
    const float* __restrict__ w0, const float* __restrict__ w1,
    const float* __restrict__ w2, const float* __restrict__ w3,
    u16* __restrict__ o0, u16* __restrict__ o1, u16* __restrict__ o2, u16* __restrict__ o3,
    float qsc) {
    int z = blockIdx.z;
    const float* in = (z == 0) ? w0 : (z == 1) ? w1 : (z == 2) ? w2 : w3;
    u16* out        = (z == 0) ? o0 : (z == 1) ? o1 : (z == 2) ? o2 : o3;
    float scale     = (z == 0) ? qsc : 1.0f;
    int i = blockIdx.x * 256 + threadIdx.x;
    float4 v = ((const float4*)in)[i];
    us4 o;
    o[0] = f2bf(v.x * scale); o[1] = f2bf(v.y * scale);
    o[2] = f2bf(v.z * scale); o[3] = f2bf(v.w * scale);
    ((us4*)out)[i] = o;
}

// kpad[b, s, :] = (s<2) ? 0 : key[b, s-2, :]   (bf16); z batches the key/value pair
__global__ __launch_bounds__(256) void cast_pad2_k(const float* __restrict__ in0, u16* __restrict__ out0,
                                                   const float* __restrict__ in1, u16* __restrict__ out1) {
    const float* in = blockIdx.z ? in1 : in0;
    u16* out        = blockIdx.z ? out1 : out0;
    int i = blockIdx.x * 256 + threadIdx.x;
    const int n4 = BB * SPAD * DM / 4;
    if (i >= n4) return;
    int e   = i * 4;
    int b   = e / (SPAD * DM);
    int rem = e - b * (SPAD * DM);
    int s   = rem >> 10;
    int d   = rem & (DM - 1);
    us4 o = {0, 0, 0, 0};
    if (s >= 2) {
        float4 v = *(const float4*)(in + (size_t)(b * SQ + (s - 2)) * DM + d);
        o[0] = f2bf(v.x); o[1] = f2bf(v.y); o[2] = f2bf(v.z); o[3] = f2bf(v.w);
    }
    ((us4*)out)[i] = o;
}

// wc2[o][r*1024+i] = conv_w[o][i][r]  (bf16)
__global__ __launch_bounds__(256) void permcast_conv_k(const float* __restrict__ cw, u16* __restrict__ wc2) {
    int i = blockIdx.x * 256 + threadIdx.x;
    const int n4 = DM * DM * 3 / 4;
    if (i >= n4) return;
    int e   = i * 4;
    int o   = e / 3072;
    int rem = e - o * 3072;
    int r   = rem >> 10;
    int ii  = rem & 1023;
    us4 q;
    #pragma unroll
    for (int t = 0; t < 4; ++t) q[t] = f2bf(cw[(size_t)(o * DM + ii + t) * 3 + r]);
    ((us4*)wc2)[i] = q;
}

// vt[(b*16+h)*64 + d][cp] = vp[b*1366 + j0 + pi(cp)][h*64+d], zero for j>=1366; row stride LCP.
// pi(cp): cp = ks*32 + quad*8 + j  ->  k = (ks + 2*(j>>2))*16 + quad*4 + (j&3).
// Matches attn's in-register P layout (PV A-frag slot (ks,quad,j) = lane's own sc value).
__global__ __launch_bounds__(256) void transpose_v_k(const u16* __restrict__ vp, u16* __restrict__ vt) {
    __shared__ u16 t[64 * 65];   // stride 65: break power-of-2 bank aliasing
    const int tid = threadIdx.x;
    const int j0 = blockIdx.x * 64;
    const int bh = blockIdx.y, b = bh >> 4, h = bh & 15;
    #pragma unroll
    for (int it = 0; it < 2; ++it) {
        int cc = tid + it * 256;
        int j = cc >> 3, d0 = (cc & 7) * 8;
        int jj = j0 + j;
        us8 v = {0, 0, 0, 0, 0, 0, 0, 0};
        if (jj < LCC) v = *(const us8*)(vp + (size_t)(b * LCC + jj) * DM + h * DKH + d0);
        #pragma unroll
        for (int q = 0; q < 8; ++q) t[(d0 + q) * 65 + j] = v[q];
    }
    __syncthreads();
    #pragma unroll
    for (int it = 0; it < 2; ++it) {
        int cc = tid + it * 256;
        int d = cc >> 3, q0 = (cc & 7) * 8;
        us8 v;
        #pragma unroll
        for (int q = 0; q < 8; ++q) {
            int cp = q0 + q;                              // stored (permuted) col
            int ks = cp >> 5, qd = (cp >> 3) & 3, j = cp & 7;
            int k  = (ks + 2 * (j >> 2)) * 16 + qd * 4 + (j & 3);   // original col
            v[q] = t[d * 65 + k];
        }
        *(us8*)(vt + (size_t)(bh * DKH + d) * LCP + j0 + q0) = v;
    }
}

// ---------------- MFMA GEMM: C[n,o] = sum_k A[n,k]*Bw[o,k] + bias[o]*bscale ----------------
// z selects problem 0/1 (batched pairs). Single-buffered (R3-proven); XCD-chunked swizzle
// co-locates the 8 column-blocks of each A-panel on one XCD for L2 reuse.
__global__ __launch_bounds__(256, 3) void gemm_mfma_k(
    const u16* __restrict__ A0, const u16* __restrict__ B0, const float* __restrict__ bias0, void* __restrict__ C0,
    const u16* __restrict__ A1, const u16* __restrict__ B1, const float* __restrict__ bias1, void* __restrict__ C1,
    int N, int K, int cf32, float bscale)
{
    // swizzled block coordinates
    int T  = gridDim.x * gridDim.y * gridDim.z;
    int i0 = blockIdx.x + gridDim.x * (blockIdx.y + gridDim.y * blockIdx.z);
    int j  = xcd_remap(i0, T);
    int bx = j % gridDim.x;
    int rem2 = j / gridDim.x;
    int by = rem2 % gridDim.y;
    int bz = rem2 / gridDim.y;

    const u16* A      = bz ? A1 : A0;
    const u16* Bw     = bz ? B1 : B0;
    const float* bias = bz ? bias1 : bias0;
    void* C           = bz ? C1 : C0;

    __shared__ u16 As[128 * 64];   // XOR-swizzled 16B chunks within each 128B row
    __shared__ u16 Bs[128 * 64];
    const int tid = threadIdx.x, wave = tid >> 6, lane = tid & 63;
    const int quad = lane >> 4, l15 = lane & 15;
    const int n0 = by * 128, o0 = bx * 128;
    const int wm = (wave >> 1) * 64, wn = (wave & 1) * 64;

    f32x4 acc[4][4];
    #pragma unroll
    for (int a = 0; a < 4; ++a)
        #pragma unroll
        for (int b = 0; b < 4; ++b)
            #pragma unroll
            for (int r = 0; r < 4; ++r) acc[a][b][r] = 0.0f;

    const int srow = (lane >> 3);
    const int sc8  = (lane & 7);

    for (int kt = 0; kt < K; kt += 64) {
        #pragma unroll
        for (int i = 0; i < 4; ++i) {
            int is  = wave * 4 + i;
            int row = is * 8 + srow;
            int c   = sc8 ^ (row & 7);
            int ra  = n0 + row; if (ra > N - 1) ra = N - 1;
            gl_lds16(A  + (size_t)ra * K + kt + c * 8,          As + is * 512 + lane * 8);
            gl_lds16(Bw + (size_t)(o0 + row) * K + kt + c * 8,  Bs + is * 512 + lane * 8);
        }
        __syncthreads();
        #pragma unroll
        for (int ks = 0; ks < 2; ++ks) {
            short8 af[4], bf[4];
            #pragma unroll
            for (int mi = 0; mi < 4; ++mi) {
                int m = wm + mi * 16 + l15;
                int c = (ks * 4 + quad) ^ (m & 7);
                af[mi] = *(const short8*)(As + m * 64 + c * 8);
            }
            #pragma unroll
            for (int nj = 0; nj < 4; ++nj) {
                int n = wn + nj * 16 + l15;
                int c = (ks * 4 + quad) ^ (n & 7);
                bf[nj] = *(const short8*)(Bs + n * 64 + c * 8);
            }
            #pragma unroll
            for (int mi = 0; mi < 4; ++mi)
                #pragma unroll
                for (int nj = 0; nj < 4; ++nj)
                    acc[mi][nj] = __builtin_amdgcn_mfma_f32_16x16x32_bf16(af[mi], bf[nj], acc[mi][nj], 0, 0, 0);
        }
        __syncthreads();
    }
    #pragma unroll
    for (int mi = 0; mi < 4; ++mi) {
        #pragma unroll
        for (int r = 0; r < 4; ++r) {
            int n = n0 + wm + mi * 16 + quad * 4 + r;
            if (n < N) {
                #pragma unroll
                for (int nj = 0; nj < 4; ++nj) {
                    int o = o0 + wn + nj * 16 + l15;
                    float v = acc[mi][nj][r] + bias[o] * bscale;
                    if (cf32) ((float*)C)[(size_t)n * DM + o] = v;
                    else      ((u16*)C)[(size_t)n * DM + o] = f2bf(v);
                }
            }
        }
    }
}

// ---------------- MFMA flash attention, swapped-QK in-register softmax ----------------
// QK^T computed as mfma(K, Q) -> S[k][q]; P stays in registers (32 exp2 + 16 cvt_pk/tile).
// V columns pre-permuted by pi (transpose_v_k) so P fragments feed PV directly.
// Row-sums via MFMA against a ones-B-fragment. XCD-chunked swizzle for K/V L2 reuse.
__global__ __launch_bounds__(256, 3) void attn_mfma_k(
    const u16* __restrict__ qp, const u16* __restrict__ kp,
    const u16* __restrict__ vt, u16* __restrict__ xo)
{
    __shared__ u16 lds[4 * 4096];   // 32 KB: [buf0: K|V][buf1: K|V]; Q staged through buf0 region
    const int tid = threadIdx.x, wave = tid >> 6, lane = tid & 63;
    const int quad = lane >> 4, l15 = lane & 15;

    int T  = gridDim.x * gridDim.y;
    int i0 = blockIdx.x + gridDim.x * blockIdx.y;
    int j5 = xcd_remap(i0, T);
    int bxs = j5 % gridDim.x;
    int bh  = j5 / gridDim.x;

    const int b = bh >> 4, h = bh & 15;
    const int s0 = bxs * 128;
    const int wq = wave * 32;
    const int srow = lane >> 3, sc8 = lane & 7;

    // ---- stage Q (128x64) into lds[0:8192] (overlaps buf0), then hoist to registers ----
    #pragma unroll
    for (int i = 0; i < 4; ++i) {
        int is = wave * 4 + i;
        int row = is * 8 + srow;
        int c = sc8 ^ (row & 7);
        gl_lds16(qp + (size_t)(b * SQ + s0 + row) * DM + h * DKH + c * 8,
                 lds + is * 512 + lane * 8);
    }
    __syncthreads();
    short8 qfr[2][2];   // [qg][ks]: B-frag = 8 contiguous d at row q = wq + qg*16 + l15
    #pragma unroll
    for (int qg = 0; qg < 2; ++qg) {
        int m = wq + qg * 16 + l15;
        #pragma unroll
        for (int ks = 0; ks < 2; ++ks) {
            int c = (ks * 4 + quad) ^ (m & 7);
            qfr[qg][ks] = *(const short8*)(lds + m * 64 + c * 8);
        }
    }
    __syncthreads();   // all waves done reading Q before buf0 overwrite

    f32x4 oacc[2][4], lacc[2];
    #pragma unroll
    for (int a = 0; a < 2; ++a) {
        #pragma unroll
        for (int r = 0; r < 4; ++r) lacc[a][r] = 0.0f;
        #pragma unroll
        for (int d = 0; d < 4; ++d)
            #pragma unroll
            for (int r = 0; r < 4; ++r) oacc[a][d][r] = 0.0f;
    }
    union { unsigned u[4]; short8 s; } onesu;
    #pragma unroll
    for (int i = 0; i < 4; ++i) onesu.u[i] = 0x3f803f80u;   // bf16 1.0 x8
    const short8 ones = onesu.s;

    // stage tile 0 into buf0
    #pragma unroll
    for (int i = 0; i < 2; ++i) {
        int is = wave * 2 + i;
        int row = is * 8 + srow;
        int c = sc8 ^ (row & 7);
        int j = row; if (j > LCC - 1) j = LCC - 1;
        gl_lds16(kp + (size_t)(b * LCC + j) * DM + h * DKH + c * 8, lds + is * 512 + lane * 8);
        gl_lds16(vt + (size_t)(bh * DKH + row) * LCP + c * 8,       lds + 4096 + is * 512 + lane * 8);
    }

    int cur = 0;
    for (int t = 0; t < 22; ++t) {
        const int j0 = t * 64;
        __syncthreads();               // publish buf[cur] (drains its gl_lds)
        if (t < 21) {                  // prefetch next tile under this tile's compute
            int nj0 = j0 + 64;
            u16* base = lds + (cur ^ 1) * 8192;
            #pragma unroll
            for (int i = 0; i < 2; ++i) {
                int is = wave * 2 + i;
                int row = is * 8 + srow;
                int c = sc8 ^ (row & 7);
                int j = nj0 + row; if (j > LCC - 1) j = LCC - 1;
                gl_lds16(kp + (size_t)(b * LCC + j) * DM + h * DKH + c * 8, base + is * 512 + lane * 8);
                gl_lds16(vt + (size_t)(bh * DKH + row) * LCP + nj0 + c * 8, base + 4096 + is * 512 + lane * 8);
            }
        }
        const u16* Kb = lds + cur * 8192;
        const u16* Vb = Kb + 4096;

        // ---- QK^T (A = K-tile rows, B = Q): sc[qg][nj] = S[k][q] ----
        f32x4 sc[2][4];
        #pragma unroll
        for (int a = 0; a < 2; ++a)
            #pragma unroll
            for (int n = 0; n < 4; ++n)
                #pragma unroll
                for (int r = 0; r < 4; ++r) sc[a][n][r] = 0.0f;
        __builtin_amdgcn_s_setprio(1);
        #pragma unroll
        for (int ks = 0; ks < 2; ++ks) {
            short8 kfr[4];
            #pragma unroll
            for (int nj = 0; nj < 4; ++nj) {
                int n = nj * 16 + l15;
                int c = (ks * 4 + quad) ^ (n & 7);
                kfr[nj] = *(const short8*)(Kb + n * 64 + c * 8);
            }
            #pragma unroll
            for (int qg = 0; qg < 2; ++qg)
                #pragma unroll
                for (int nj = 0; nj < 4; ++nj)
                    sc[qg][nj] = __builtin_amdgcn_mfma_f32_16x16x32_bf16(kfr[nj], qfr[qg][ks], sc[qg][nj], 0, 0, 0);
        }
        __builtin_amdgcn_s_setprio(0);

        // ---- softmax in-register: P = exp2(S) (scale folded into Wq), mask tail k ----
        const bool tail = (j0 + 64 > LCC);
        #pragma unroll
        for (int qg = 0; qg < 2; ++qg) {
            #pragma unroll
            for (int nj = 0; nj < 4; ++nj) {
                #pragma unroll
                for (int r = 0; r < 4; ++r) {
                    float p = __builtin_amdgcn_exp2f(sc[qg][nj][r]);
                    if (tail && (j0 + nj * 16 + quad * 4 + r) >= LCC) p = 0.0f;
                    sc[qg][nj][r] = p;
                }
            }
        }
        // ---- pack P into PV A-frags (lane-local; slot j -> (nj = ks+2*(j>>2), r = j&3)) ----
        short8 pa[2][2];
        #pragma unroll
        for (int qg = 0; qg < 2; ++qg) {
            #pragma unroll
            for (int ks = 0; ks < 2; ++ks) {
                unsigned w0, w1, w2, w3;
                asm("v_cvt_pk_bf16_f32 %0, %1, %2" : "=v"(w0) : "v"(sc[qg][ks][0]),     "v"(sc[qg][ks][1]));
                asm("v_cvt_pk_bf16_f32 %0, %1, %2" : "=v"(w1) : "v"(sc[qg][ks][2]),     "v"(sc[qg][ks][3]));
                asm("v_cvt_pk_bf16_f32 %0, %1, %2" : "=v"(w2) : "v"(sc[qg][ks + 2][0]), "v"(sc[qg][ks + 2][1]));
                asm("v_cvt_pk_bf16_f32 %0, %1, %2" : "=v"(w3) : "v"(sc[qg][ks + 2][2]), "v"(sc[qg][ks + 2][3]));
                union { unsigned u[4]; short8 s; } cv;
                cv.u[0] = w0; cv.u[1] = w1; cv.u[2] = w2; cv.u[3] = w3;
                pa[qg][ks] = cv.s;
            }
        }
        // ---- PV + row-sum: oacc += P*V, lacc += P*ones ----
        __builtin_amdgcn_s_setprio(1);
        #pragma unroll
        for (int ks = 0; ks < 2; ++ks) {
            short8 vfr[4];
            #pragma unroll
            for (int dj = 0; dj < 4; ++dj) {
                int d = dj * 16 + l15;
                int c = (ks * 4 + quad) ^ (d & 7);
                vfr[dj] = *(const short8*)(Vb + d * 64 + c * 8);
            }
            #pragma unroll
            for (int qg = 0; qg < 2; ++qg) {
                #pragma unroll
                for (int dj = 0; dj < 4; ++dj)
                    oacc[qg][dj] = __builtin_amdgcn_mfma_f32_16x16x32_bf16(pa[qg][ks], vfr[dj], oacc[qg][dj], 0, 0, 0);
                lacc[qg] = __builtin_amdgcn_mfma_f32_16x16x32_bf16(pa[qg][ks], ones, lacc[qg], 0, 0, 0);
            }
        }
        __builtin_amdgcn_s_setprio(0);
        cur ^= 1;
    }

    // ---- epilogue: lacc[qg][r] already holds the row-sum for output row quad*4+r ----
    #pragma unroll
    for (int qg = 0; qg < 2; ++qg) {
        #pragma unroll
        for (int r = 0; r < 4; ++r) {
            float inv = 1.0f / lacc[qg][r];
            int s = s0 + wq + qg * 16 + quad * 4 + r;
            #pragma unroll
            for (int dj = 0; dj < 4; ++dj)
                xo[(size_t)(b * SQ + s) * DM + h * DKH + dj * 16 + l15] = f2bf(oacc[qg][dj][r] * inv);
        }
    }
}

extern "C" void kernel_launch(void* const* d_in, const int* in_sizes, int n_in,
                              void* d_out, int out_size, void* d_ws, size_t ws_size,
                              hipStream_t stream)
{
    const float* query  = (const float*)d_in[0];
    const float* key    = (const float*)d_in[1];
    const float* value  = (const float*)d_in[2];
    const float* Wq     = (const float*)d_in[3];
    const float* bq     = (const float*)d_in[4];
    const float* Wk     = (const float*)d_in[5];
    const float* bk     = (const float*)d_in[6];
    const float* Wv     = (const float*)d_in[7];
    const float* bv     = (const float*)d_in[8];
    const float* Wo     = (const float*)d_in[9];
    const float* bo     = (const float*)d_in[10];
    const float* conv_w = (const float*)d_in[11];
    const float* conv_b = (const float*)d_in[12];
    float* out = (float*)d_out;

    u16* p = (u16*)d_ws;
    auto alloc = [&](size_t n) { u16* r = p; p += (n + 127) & ~(size_t)127; return r; };
    u16* qbf  = alloc((size_t)BB * SQ * DM);
    u16* kpad = alloc((size_t)BB * SPAD * DM);
    u16* vpad = alloc((size_t)BB * SPAD * DM);
    u16* wqb  = alloc((size_t)DM * DM);
    u16* wkb  = alloc((size_t)DM * DM);
    u16* wvb  = alloc((size_t)DM * DM);
    u16* wob  = alloc((size_t)DM * DM);
    u16* wc2b = alloc((size_t)DM * DM * 3);
    u16* kc   = alloc((size_t)BB * LCC * DM);
    u16* vc   = alloc((size_t)BB * LCC * DM);
    u16* kpj  = alloc((size_t)BB * LCC * DM);
    u16* vpj  = alloc((size_t)BB * LCC * DM);
    u16* qprj = alloc((size_t)BB * SQ * DM);
    u16* vtb  = alloc((size_t)BB * NH * DKH * LCP);
    u16* xo   = alloc((size_t)BB * SQ * DM);

    const int NC = BB * LCC;    // 5464
    const int NS = BB * SQ;     // 16384

    cast4_k<<<dim3(NS * DM / 4 / 256), 256, 0, stream>>>(query, qbf, NS * DM / 4, 1.0f);
    cast_pad2_k<<<dim3((BB * SPAD * DM / 4 + 255) / 256, 1, 2), 256, 0, stream>>>(key, kpad, value, vpad);
    cast4w_k<<<dim3(DM * DM / 4 / 256, 1, 4), 256, 0, stream>>>(Wq, Wk, Wv, Wo, wqb, wkb, wvb, wob, QSC);
    permcast_conv_k<<<dim3(DM * DM * 3 / 4 / 256), 256, 0, stream>>>(conv_w, wc2b);

    // conv compression as plain GEMM (batched pair): kpad flat view (B*1366, 3072) IS the im2col
    gemm_mfma_k<<<dim3(8, 43, 2), 256, 0, stream>>>(kpad, wc2b, conv_b, kc,
                                                    vpad, wc2b, conv_b, vc, NC, 3072, 0, 1.0f);

    // q projection (1/8*log2e folded into weights+bias)
    gemm_mfma_k<<<dim3(8, 128, 1), 256, 0, stream>>>(qbf, wqb, bq, qprj,
                                                     qbf, wqb, bq, qprj, NS, DM, 0, QSC);
    // k/v projections (batched pair)
    gemm_mfma_k<<<dim3(8, 43, 2), 256, 0, stream>>>(kc, wkb, bk, kpj,
                                                    vc, wvb, bv, vpj, NC, DM, 0, 1.0f);

    transpose_v_k<<<dim3(22, BB * NH), 256, 0, stream>>>(vpj, vtb);

    attn_mfma_k<<<dim3(SQ / 128, BB * NH), 256, 0, stream>>>(qprj, kpj, vtb, xo);

    gemm_mfma_k<<<dim3(8, 128, 1), 256, 0, stream>>>(xo, wob, bo, out,
                                                     xo, wob, bo, out, NS, DM, 1, 1.0f);
}